// Round 5
// baseline (157.570 us; speedup 1.0000x reference)
//
#include <hip/hip_runtime.h>
#include <hip/hip_bf16.h>
#include <hip/hip_cooperative_groups.h>

namespace cg = cooperative_groups;

// Problem constants
constexpr int B  = 4;
constexpr int N  = 10000;
constexpr int E  = 160000;
constexpr int F  = 64;     // F_IN
constexpr int DA = 128;    // D_ATT
constexpr int H  = 8;
constexpr int DK = 16;
constexpr int TOTAL = B * N;   // 40000 rows

constexpr int NBLK = 256;          // gather blocks per b (grid = 4*256 = 1024, co-resident at 4 blk/CU)
constexpr int EPB  = E / NBLK;     // 625 edges per block (exact)
constexpr int EPW  = 157;          // ceil(625/4) edges per wave
constexpr int NRND = 10;           // ceil(157/16) rounds

typedef __attribute__((ext_vector_type(8))) short short8v;  // 8 bf16 (4 VGPRs)
typedef __attribute__((ext_vector_type(4))) float f32x4;
typedef __attribute__((ext_vector_type(2))) float f32x2;

__device__ __forceinline__ unsigned pack_bf16(float a, float b) {
    unsigned ua = __builtin_bit_cast(unsigned, a);
    unsigned ub = __builtin_bit_cast(unsigned, b);
    ua = (ua + 0x7fffu + ((ua >> 16) & 1u)) >> 16;   // RNE
    ub = (ub + 0x7fffu + ((ub >> 16) & 1u)) >> 16;
    return ua | (ub << 16);
}
__device__ __forceinline__ short8v cvt8(float4 a, float4 b) {
    union { unsigned u[4]; short8v s; } r;
    r.u[0] = pack_bf16(a.x, a.y);
    r.u[1] = pack_bf16(a.z, a.w);
    r.u[2] = pack_bf16(b.x, b.y);
    r.u[3] = pack_bf16(b.z, b.w);
    return r.s;
}
__device__ __forceinline__ void ocomb(float& m, float& s, float m2, float s2) {
    float M = fmaxf(m, m2);
    s = s * __expf(m - M) + s2 * __expf(m2 - M);
    m = M;
}
// q,k dwords = 4 fp8 covering 4 consecutive heads; accumulate into two f32x2.
__device__ __forceinline__ void fp8dot(unsigned q, unsigned k, f32x2& olo, f32x2& ohi) {
    f32x2 ql = __builtin_amdgcn_cvt_pk_f32_fp8((int)q, false);
    f32x2 qh = __builtin_amdgcn_cvt_pk_f32_fp8((int)q, true);
    f32x2 kl = __builtin_amdgcn_cvt_pk_f32_fp8((int)k, false);
    f32x2 kh = __builtin_amdgcn_cvt_pk_f32_fp8((int)k, true);
    olo += ql * kl;
    ohi += qh * kh;
}

// ---------------------------------------------------------------------------
// K1: MFMA projections. grid = (313 node-blocks, 3 matrices).
// Layout p = d*8 + h (head-transposed). q/k stored as fp8 e4m3 (q pre-scaled
// by 1/sqrt(DK)); v stored f32 to d_out.
// ---------------------------------------------------------------------------
__global__ __launch_bounds__(256) void proj_mfma(
    const float* __restrict__ x,
    const float* __restrict__ Qw, const float* __restrict__ Qb,
    const float* __restrict__ Kw, const float* __restrict__ Kb,
    const float* __restrict__ Vw, const float* __restrict__ Vb,
    unsigned char* __restrict__ qws, unsigned char* __restrict__ kws,
    float* __restrict__ vout)
{
    const int t    = threadIdx.x;
    const int w    = t >> 6;        // wave 0..3
    const int lane = t & 63;
    const int tn   = lane & 15;
    const int g    = lane >> 4;     // 0..3

    const int mat = blockIdx.y;
    const float* W    = (mat == 0) ? Qw : (mat == 1) ? Kw : Vw;
    const float* bias = (mat == 0) ? Qb : (mat == 1) ? Kb : Vb;
    unsigned char* qk_dst = (mat == 0) ? qws : kws;
    const float qsc = (mat == 0) ? 0.25f : 1.0f;    // 1/sqrt(DK) folded into q

    short8v bf[8][2];
    float bv[8];
    #pragma unroll
    for (int a0t = 0; a0t < 8; ++a0t) {
        bv[a0t] = bias[a0t * 16 + tn];
        const float4* wr = (const float4*)(W + (size_t)(a0t * 16 + tn) * F);
        bf[a0t][0] = cvt8(wr[g * 2],     wr[g * 2 + 1]);
        bf[a0t][1] = cvt8(wr[8 + g * 2], wr[8 + g * 2 + 1]);
    }

    #pragma unroll
    for (int rt = 0; rt < 2; ++rt) {
        const int m0t = blockIdx.x * 128 + rt * 64 + w * 16;
        if (m0t >= TOTAL) break;

        const float4* xr = (const float4*)(x + (size_t)(m0t + tn) * F);
        short8v a0 = cvt8(xr[g * 2],     xr[g * 2 + 1]);
        short8v a1 = cvt8(xr[8 + g * 2], xr[8 + g * 2 + 1]);

        f32x4 acc[8];
        #pragma unroll
        for (int a0t = 0; a0t < 8; ++a0t) {
            acc[a0t][0] = bv[a0t]; acc[a0t][1] = bv[a0t];
            acc[a0t][2] = bv[a0t]; acc[a0t][3] = bv[a0t];
        }
        #pragma unroll
        for (int a0t = 0; a0t < 8; ++a0t) {
            acc[a0t] = __builtin_amdgcn_mfma_f32_16x16x32_bf16(a0, bf[a0t][0], acc[a0t], 0, 0, 0);
            acc[a0t] = __builtin_amdgcn_mfma_f32_16x16x32_bf16(a1, bf[a0t][1], acc[a0t], 0, 0, 0);
        }

        if (mat < 2) {
            #pragma unroll
            for (int r = 0; r < 4; ++r) {
                const int node = m0t + g * 4 + r;
                unsigned u0 = (unsigned)__builtin_amdgcn_cvt_pk_fp8_f32(
                                  acc[0][r] * qsc, acc[1][r] * qsc, 0, false);
                u0 = (unsigned)__builtin_amdgcn_cvt_pk_fp8_f32(
                                  acc[2][r] * qsc, acc[3][r] * qsc, (int)u0, true);
                unsigned u1 = (unsigned)__builtin_amdgcn_cvt_pk_fp8_f32(
                                  acc[4][r] * qsc, acc[5][r] * qsc, 0, false);
                u1 = (unsigned)__builtin_amdgcn_cvt_pk_fp8_f32(
                                  acc[6][r] * qsc, acc[7][r] * qsc, (int)u1, true);
                *(uint2*)(qk_dst + (size_t)node * DA + tn * 8) = make_uint2(u0, u1);
            }
        } else {
            #pragma unroll
            for (int r = 0; r < 4; ++r) {
                const int node = m0t + g * 4 + r;
                float* vb = vout + (size_t)node * DA + tn * 8;
                *(float4*)vb       = make_float4(acc[0][r], acc[1][r], acc[2][r], acc[3][r]);
                *(float4*)(vb + 4) = make_float4(acc[4][r], acc[5][r], acc[6][r], acc[7][r]);
            }
        }
    }
}

// ---------------------------------------------------------------------------
// K2 (cooperative): gather + dot + softmax partials ; grid.sync() ;
// per-block (M,1/S) reduction ; normalize own chunk (L2-resident).
// 4 lanes per edge, fp8 rows, 2 uint4 loads per lane per edge.
// grid = (B, NBLK): linear id % 4 == b -> per-XCD L2 holds one b's q/k.
// ---------------------------------------------------------------------------
__global__ __launch_bounds__(256, 4) void gather_sm_fused(
    const unsigned char* __restrict__ qws, const unsigned char* __restrict__ kws,
    const int* __restrict__ edge, float* __restrict__ att,
    float2* __restrict__ partials)
{
    const int b   = blockIdx.x;
    const int blk = blockIdx.y;
    const int t = threadIdx.x;
    const int w = t >> 6, lane = t & 63;
    const int g = lane >> 2, i = lane & 3;

    const unsigned char* qb = qws + (size_t)b * N * DA;
    const unsigned char* kb = kws + (size_t)b * N * DA;
    float* attb = att + (size_t)b * E * H;

    const int e0   = blk * EPB;                      // block edge base
    const int ew0  = e0 + w * EPW;                   // wave edge base
    const int wend = min(e0 + EPB, ew0 + EPW);       // wave edge end

    float ma0 = -3.0e38f, sa0 = 0.f, ma1 = -3.0e38f, sa1 = 0.f;

    #pragma unroll 1
    for (int r = 0; r < NRND; ++r) {
        const int el = ew0 + r * 16 + g;
        const bool valid = el < wend;
        const int eidx = valid ? el : 0;
        const int s = edge[eidx];
        const int d = edge[E + eidx];
        const uint4* qp = (const uint4*)(qb + (size_t)s * DA) + i;
        const uint4* kp = (const uint4*)(kb + (size_t)d * DA) + i;
        uint4 q0 = qp[0], q1 = qp[4];
        uint4 k0 = kp[0], k1 = kp[4];

        f32x2 o01 = {0.f, 0.f}, o23 = {0.f, 0.f}, o45 = {0.f, 0.f}, o67 = {0.f, 0.f};
        fp8dot(q0.x, k0.x, o01, o23);
        fp8dot(q0.y, k0.y, o45, o67);
        fp8dot(q0.z, k0.z, o01, o23);
        fp8dot(q0.w, k0.w, o45, o67);
        fp8dot(q1.x, k1.x, o01, o23);
        fp8dot(q1.y, k1.y, o45, o67);
        fp8dot(q1.z, k1.z, o01, o23);
        fp8dot(q1.w, k1.w, o45, o67);

        #pragma unroll
        for (int off = 1; off <= 2; off <<= 1) {
            o01[0] += __shfl_xor(o01[0], off);  o01[1] += __shfl_xor(o01[1], off);
            o23[0] += __shfl_xor(o23[0], off);  o23[1] += __shfl_xor(o23[1], off);
            o45[0] += __shfl_xor(o45[0], off);  o45[1] += __shfl_xor(o45[1], off);
            o67[0] += __shfl_xor(o67[0], off);  o67[1] += __shfl_xor(o67[1], off);
        }

        f32x2 pp = (i == 0) ? o01 : (i == 1) ? o23 : (i == 2) ? o45 : o67;
        if (valid) {
            *(f32x2*)(attb + (size_t)el * H + 2 * i) = pp;
            float p0 = pp[0], p1 = pp[1];
            if (p0 > ma0) { sa0 = sa0 * __expf(ma0 - p0) + 1.f; ma0 = p0; }
            else          { sa0 += __expf(p0 - ma0); }
            if (p1 > ma1) { sa1 = sa1 * __expf(ma1 - p1) + 1.f; ma1 = p1; }
            else          { sa1 += __expf(p1 - ma1); }
        }
    }

    // wave-level combine across the 16 groups (lanes with equal i)
    #pragma unroll
    for (int off = 4; off <= 32; off <<= 1) {
        float m2 = __shfl_xor(ma0, off), s2 = __shfl_xor(sa0, off);
        ocomb(ma0, sa0, m2, s2);
        m2 = __shfl_xor(ma1, off); s2 = __shfl_xor(sa1, off);
        ocomb(ma1, sa1, m2, s2);
    }

    __shared__ float4 red[4][4];
    if (g == 0) red[w][i] = make_float4(ma0, sa0, ma1, sa1);
    __syncthreads();
    if (t < 4) {
        float m0f = -3.0e38f, s0f = 0.f, m1f = -3.0e38f, s1f = 0.f;
        #pragma unroll
        for (int ww = 0; ww < 4; ++ww) {
            float4 v = red[ww][t];
            ocomb(m0f, s0f, v.x, v.y);
            ocomb(m1f, s1f, v.z, v.w);
        }
        partials[((size_t)b * H + 2 * t)     * NBLK + blk] = make_float2(m0f, s0f);
        partials[((size_t)b * H + 2 * t + 1) * NBLK + blk] = make_float2(m1f, s1f);
    }

    // ---- grid-wide barrier: partials + logits visible device-wide ----
    cg::this_grid().sync();

    // Phase 2a: per-block (M, 1/S) for all 8 heads of this b.
    // wave w reduces heads 2w, 2w+1 over NBLK=256 partials (4 iters/lane).
    __shared__ float2 msh[H];
    {
        const float2* p0 = partials + ((size_t)b * H + 2 * w) * NBLK;
        const float2* p1 = partials + ((size_t)b * H + 2 * w + 1) * NBLK;
        float m0 = -3.0e38f, s0 = 0.f, m1 = -3.0e38f, s1 = 0.f;
        #pragma unroll
        for (int c = 0; c < NBLK / 64; ++c) {
            float2 v0 = p0[lane + c * 64];
            float2 v1 = p1[lane + c * 64];
            ocomb(m0, s0, v0.x, v0.y);
            ocomb(m1, s1, v1.x, v1.y);
        }
        #pragma unroll
        for (int off = 1; off < 64; off <<= 1) {
            float m2 = __shfl_xor(m0, off), s2 = __shfl_xor(s0, off);
            ocomb(m0, s0, m2, s2);
            m2 = __shfl_xor(m1, off); s2 = __shfl_xor(s1, off);
            ocomb(m1, s1, m2, s2);
        }
        if (lane == 0) {
            msh[2 * w]     = make_float2(m0, 1.0f / s0);
            msh[2 * w + 1] = make_float2(m1, 1.0f / s1);
        }
    }
    __syncthreads();

    // Phase 2b: normalize this block's own chunk (written pre-barrier by this
    // block -> resident in this XCD's L2). EPB*H/2 = 2500 float2.
    {
        float2* ap = (float2*)(attb + (size_t)e0 * H);
        for (int j = t; j < EPB * H / 2; j += 256) {
            float2 v = ap[j];
            const int h0 = (j & 3) * 2;
            float2 mlo = msh[h0], mhi = msh[h0 + 1];
            v.x = __expf(v.x - mlo.x) * mlo.y;
            v.y = __expf(v.y - mhi.x) * mhi.y;
            ap[j] = v;
        }
    }
}

extern "C" void kernel_launch(void* const* d_in, const int* in_sizes, int n_in,
                              void* d_out, int out_size, void* d_ws, size_t ws_size,
                              hipStream_t stream)
{
    const float* x  = (const float*)d_in[0];
    const float* Qw = (const float*)d_in[1];
    const float* Qb = (const float*)d_in[2];
    const float* Kw = (const float*)d_in[3];
    const float* Kb = (const float*)d_in[4];
    const float* Vw = (const float*)d_in[5];
    const float* Vb = (const float*)d_in[6];
    const int*   edge = (const int*)d_in[7];

    float* out  = (float*)d_out;
    float* att  = out;                                // B*E*H
    float* vout = out + (size_t)B * E * H;            // B*N*DK*H

    char* w = (char*)d_ws;
    unsigned char* qws = (unsigned char*)w;                       // 5.12 MB fp8
    unsigned char* kws = qws + (size_t)B * N * DA;                // 5.12 MB fp8
    float2* partials = (float2*)(w + 2 * (size_t)B * N * DA);     // 64 KB

    hipLaunchKernelGGL(proj_mfma, dim3((TOTAL + 127) / 128, 3), dim3(256), 0, stream,
                       x, Qw, Qb, Kw, Kb, Vw, Vb, qws, kws, vout);

    void* args[] = { (void*)&qws, (void*)&kws, (void*)&edge, (void*)&att, (void*)&partials };
    hipLaunchCooperativeKernel((const void*)gather_sm_fused, dim3(B, NBLK), dim3(256),
                               args, 0, stream);
}

// Round 6
// 55.314 us; speedup vs baseline: 2.8487x; 2.8487x over previous
//
#include <hip/hip_runtime.h>
#include <hip/hip_bf16.h>

// Problem constants
constexpr int B  = 4;
constexpr int N  = 10000;
constexpr int E  = 160000;
constexpr int F  = 64;     // F_IN
constexpr int DA = 128;    // D_ATT
constexpr int H  = 8;
constexpr int DK = 16;
constexpr int TOTAL = B * N;   // 40000 rows

constexpr int EPB  = 512;                   // edges per block (gather)
constexpr int NBLK = (E + EPB - 1) / EPB;   // 313 blocks per b

typedef __attribute__((ext_vector_type(8))) short short8v;  // 8 bf16 (4 VGPRs)
typedef __attribute__((ext_vector_type(4))) float f32x4;
typedef __attribute__((ext_vector_type(2))) float f32x2;

__device__ __forceinline__ unsigned pack_bf16(float a, float b) {
    unsigned ua = __builtin_bit_cast(unsigned, a);
    unsigned ub = __builtin_bit_cast(unsigned, b);
    ua = (ua + 0x7fffu + ((ua >> 16) & 1u)) >> 16;   // RNE
    ub = (ub + 0x7fffu + ((ub >> 16) & 1u)) >> 16;
    return ua | (ub << 16);
}
__device__ __forceinline__ short8v cvt8(float4 a, float4 b) {
    union { unsigned u[4]; short8v s; } r;
    r.u[0] = pack_bf16(a.x, a.y);
    r.u[1] = pack_bf16(a.z, a.w);
    r.u[2] = pack_bf16(b.x, b.y);
    r.u[3] = pack_bf16(b.z, b.w);
    return r.s;
}
// q,k dwords = 4 fp8 covering 4 consecutive heads; accumulate into two f32x2.
__device__ __forceinline__ void fp8dot(unsigned q, unsigned k, f32x2& olo, f32x2& ohi) {
    f32x2 ql = __builtin_amdgcn_cvt_pk_f32_fp8((int)q, false);
    f32x2 qh = __builtin_amdgcn_cvt_pk_f32_fp8((int)q, true);
    f32x2 kl = __builtin_amdgcn_cvt_pk_f32_fp8((int)k, false);
    f32x2 kh = __builtin_amdgcn_cvt_pk_f32_fp8((int)k, true);
    olo += ql * kl;
    ohi += qh * kh;
}

// ---------------------------------------------------------------------------
// K1: MFMA projections. grid = (313 node-blocks, 3 matrices).
// Layout p = d*8 + h (head-transposed). q/k stored as fp8 e4m3 (q pre-scaled
// by 1/sqrt(DK)); v stored f32 to d_out.
// ---------------------------------------------------------------------------
__global__ __launch_bounds__(256) void proj_mfma(
    const float* __restrict__ x,
    const float* __restrict__ Qw, const float* __restrict__ Qb,
    const float* __restrict__ Kw, const float* __restrict__ Kb,
    const float* __restrict__ Vw, const float* __restrict__ Vb,
    unsigned char* __restrict__ qws, unsigned char* __restrict__ kws,
    float* __restrict__ vout)
{
    const int t    = threadIdx.x;
    const int w    = t >> 6;        // wave 0..3
    const int lane = t & 63;
    const int tn   = lane & 15;
    const int g    = lane >> 4;     // 0..3

    const int mat = blockIdx.y;
    const float* W    = (mat == 0) ? Qw : (mat == 1) ? Kw : Vw;
    const float* bias = (mat == 0) ? Qb : (mat == 1) ? Kb : Vb;
    unsigned char* qk_dst = (mat == 0) ? qws : kws;
    const float qsc = (mat == 0) ? 0.25f : 1.0f;    // 1/sqrt(DK) folded into q

    short8v bf[8][2];
    float bv[8];
    #pragma unroll
    for (int a0t = 0; a0t < 8; ++a0t) {
        bv[a0t] = bias[a0t * 16 + tn];
        const float4* wr = (const float4*)(W + (size_t)(a0t * 16 + tn) * F);
        bf[a0t][0] = cvt8(wr[g * 2],     wr[g * 2 + 1]);
        bf[a0t][1] = cvt8(wr[8 + g * 2], wr[8 + g * 2 + 1]);
    }

    #pragma unroll
    for (int rt = 0; rt < 2; ++rt) {
        const int m0t = blockIdx.x * 128 + rt * 64 + w * 16;
        if (m0t >= TOTAL) break;

        const float4* xr = (const float4*)(x + (size_t)(m0t + tn) * F);
        short8v a0 = cvt8(xr[g * 2],     xr[g * 2 + 1]);
        short8v a1 = cvt8(xr[8 + g * 2], xr[8 + g * 2 + 1]);

        f32x4 acc[8];
        #pragma unroll
        for (int a0t = 0; a0t < 8; ++a0t) {
            acc[a0t][0] = bv[a0t]; acc[a0t][1] = bv[a0t];
            acc[a0t][2] = bv[a0t]; acc[a0t][3] = bv[a0t];
        }
        #pragma unroll
        for (int a0t = 0; a0t < 8; ++a0t) {
            acc[a0t] = __builtin_amdgcn_mfma_f32_16x16x32_bf16(a0, bf[a0t][0], acc[a0t], 0, 0, 0);
            acc[a0t] = __builtin_amdgcn_mfma_f32_16x16x32_bf16(a1, bf[a0t][1], acc[a0t], 0, 0, 0);
        }

        if (mat < 2) {
            #pragma unroll
            for (int r = 0; r < 4; ++r) {
                const int node = m0t + g * 4 + r;
                unsigned u0 = (unsigned)__builtin_amdgcn_cvt_pk_fp8_f32(
                                  acc[0][r] * qsc, acc[1][r] * qsc, 0, false);
                u0 = (unsigned)__builtin_amdgcn_cvt_pk_fp8_f32(
                                  acc[2][r] * qsc, acc[3][r] * qsc, (int)u0, true);
                unsigned u1 = (unsigned)__builtin_amdgcn_cvt_pk_fp8_f32(
                                  acc[4][r] * qsc, acc[5][r] * qsc, 0, false);
                u1 = (unsigned)__builtin_amdgcn_cvt_pk_fp8_f32(
                                  acc[6][r] * qsc, acc[7][r] * qsc, (int)u1, true);
                *(uint2*)(qk_dst + (size_t)node * DA + tn * 8) = make_uint2(u0, u1);
            }
        } else {
            #pragma unroll
            for (int r = 0; r < 4; ++r) {
                const int node = m0t + g * 4 + r;
                float* vb = vout + (size_t)node * DA + tn * 8;
                *(float4*)vb       = make_float4(acc[0][r], acc[1][r], acc[2][r], acc[3][r]);
                *(float4*)(vb + 4) = make_float4(acc[4][r], acc[5][r], acc[6][r], acc[7][r]);
            }
        }
    }
}

// ---------------------------------------------------------------------------
// K2: cooperative fp8 gather + dot; stores exp(logit) to att and per-block
// plain SUMS of exp (no max needed: logits bounded by ~|q||k|*DK, << 88).
// 4 lanes per edge; lane i reads bytes [16i,16i+16) and [64+16i,+16) of each
// 128B row -> one 64B line per 4-lane group per load instr.
// grid = (B, NBLK): linear id % 4 == b -> per-XCD L2 holds one b (2.56MB).
// ---------------------------------------------------------------------------
__global__ __launch_bounds__(256) void gather_dot_sm(
    const unsigned char* __restrict__ qws, const unsigned char* __restrict__ kws,
    const int* __restrict__ edge, float* __restrict__ att,
    float* __restrict__ psum)
{
    const int b   = blockIdx.x;
    const int blk = blockIdx.y;
    const int t = threadIdx.x;
    const int w = t >> 6, lane = t & 63;
    const int g = lane >> 2, i = lane & 3;

    const unsigned char* qb = qws + (size_t)b * N * DA;
    const unsigned char* kb = kws + (size_t)b * N * DA;
    float* attb = att + (size_t)b * E * H;

    const int ew0 = blk * EPB + w * (EPB / 4);   // wave's edge base

    float sa0 = 0.f, sa1 = 0.f;

    #pragma unroll 1
    for (int r = 0; r < EPB / 4 / 16; ++r) {     // 8 rounds of 16 edges
        const int el = ew0 + r * 16 + g;
        const bool valid = el < E;
        const int eidx = valid ? el : 0;
        const int s = edge[eidx];
        const int d = edge[E + eidx];
        const uint4* qp = (const uint4*)(qb + (size_t)s * DA) + i;
        const uint4* kp = (const uint4*)(kb + (size_t)d * DA) + i;
        uint4 q0 = qp[0], q1 = qp[4];
        uint4 k0 = kp[0], k1 = kp[4];

        f32x2 o01 = {0.f, 0.f}, o23 = {0.f, 0.f}, o45 = {0.f, 0.f}, o67 = {0.f, 0.f};
        fp8dot(q0.x, k0.x, o01, o23);
        fp8dot(q0.y, k0.y, o45, o67);
        fp8dot(q0.z, k0.z, o01, o23);
        fp8dot(q0.w, k0.w, o45, o67);
        fp8dot(q1.x, k1.x, o01, o23);
        fp8dot(q1.y, k1.y, o45, o67);
        fp8dot(q1.z, k1.z, o01, o23);
        fp8dot(q1.w, k1.w, o45, o67);

        // reduce across the 4 lanes of the edge group
        #pragma unroll
        for (int off = 1; off <= 2; off <<= 1) {
            o01[0] += __shfl_xor(o01[0], off);  o01[1] += __shfl_xor(o01[1], off);
            o23[0] += __shfl_xor(o23[0], off);  o23[1] += __shfl_xor(o23[1], off);
            o45[0] += __shfl_xor(o45[0], off);  o45[1] += __shfl_xor(o45[1], off);
            o67[0] += __shfl_xor(o67[0], off);  o67[1] += __shfl_xor(o67[1], off);
        }

        f32x2 pp = (i == 0) ? o01 : (i == 1) ? o23 : (i == 2) ? o45 : o67;
        if (valid) {
            float e0 = __expf(pp[0]), e1 = __expf(pp[1]);
            *(f32x2*)(attb + (size_t)el * H + 2 * i) = f32x2{e0, e1};
            sa0 += e0;
            sa1 += e1;
        }
    }

    // wave-level sum across the 16 groups (lanes with equal i)
    #pragma unroll
    for (int off = 4; off <= 32; off <<= 1) {
        sa0 += __shfl_xor(sa0, off);
        sa1 += __shfl_xor(sa1, off);
    }

    __shared__ float2 red[4][4];
    if (g == 0) red[w][i] = make_float2(sa0, sa1);
    __syncthreads();
    if (t < 4) {
        float s0f = 0.f, s1f = 0.f;
        #pragma unroll
        for (int ww = 0; ww < 4; ++ww) {
            float2 v = red[ww][t];
            s0f += v.x;
            s1f += v.y;
        }
        psum[((size_t)b * H + 2 * t)     * NBLK + blk] = s0f;
        psum[((size_t)b * H + 2 * t + 1) * NBLK + blk] = s1f;
    }
}

// ---------------------------------------------------------------------------
// K3: fused final+normalize. Each block redundantly reduces its b's 313
// partial sums per head (10KB, L2-hit), then scales its 2048-float chunk.
// grid (B, E*H/2048); wave w reduces heads 2w, 2w+1.
// ---------------------------------------------------------------------------
__global__ __launch_bounds__(256) void softmax_norm(
    float* __restrict__ att, const float* __restrict__ psum)
{
    const int b = blockIdx.x;
    const int t = threadIdx.x;
    const int w = t >> 6, lane = t & 63;

    __shared__ float inv[H];
    {
        const float* p0 = psum + ((size_t)b * H + 2 * w) * NBLK;
        const float* p1 = psum + ((size_t)b * H + 2 * w + 1) * NBLK;
        float s0 = 0.f, s1 = 0.f;
        for (int c = lane; c < NBLK; c += 64) {
            s0 += p0[c];
            s1 += p1[c];
        }
        #pragma unroll
        for (int off = 1; off < 64; off <<= 1) {
            s0 += __shfl_xor(s0, off);
            s1 += __shfl_xor(s1, off);
        }
        if (lane == 0) {
            inv[2 * w]     = 1.0f / s0;
            inv[2 * w + 1] = 1.0f / s1;
        }
    }
    __syncthreads();

    float* p = att + (size_t)b * (E * H) + (size_t)blockIdx.y * 2048 + t * 8;
    float4 lo = *(float4*)p;
    float4 hi = *(float4*)(p + 4);
    lo.x *= inv[0];  lo.y *= inv[1];  lo.z *= inv[2];  lo.w *= inv[3];
    hi.x *= inv[4];  hi.y *= inv[5];  hi.z *= inv[6];  hi.w *= inv[7];
    *(float4*)p       = lo;
    *(float4*)(p + 4) = hi;
}

extern "C" void kernel_launch(void* const* d_in, const int* in_sizes, int n_in,
                              void* d_out, int out_size, void* d_ws, size_t ws_size,
                              hipStream_t stream)
{
    const float* x  = (const float*)d_in[0];
    const float* Qw = (const float*)d_in[1];
    const float* Qb = (const float*)d_in[2];
    const float* Kw = (const float*)d_in[3];
    const float* Kb = (const float*)d_in[4];
    const float* Vw = (const float*)d_in[5];
    const float* Vb = (const float*)d_in[6];
    const int*   edge = (const int*)d_in[7];

    float* out  = (float*)d_out;
    float* att  = out;                                // B*E*H
    float* vout = out + (size_t)B * E * H;            // B*N*DK*H

    char* w = (char*)d_ws;
    unsigned char* qws = (unsigned char*)w;                       // 5.12 MB fp8
    unsigned char* kws = qws + (size_t)B * N * DA;                // 5.12 MB fp8
    float* psum = (float*)(w + 2 * (size_t)B * N * DA);           // 40 KB

    hipLaunchKernelGGL(proj_mfma, dim3((TOTAL + 127) / 128, 3), dim3(256), 0, stream,
                       x, Qw, Qb, Kw, Kb, Vw, Vb, qws, kws, vout);
    hipLaunchKernelGGL(gather_dot_sm, dim3(B, NBLK), dim3(256), 0, stream,
                       qws, kws, edge, att, psum);
    hipLaunchKernelGGL(softmax_norm, dim3(B, (E * H) / 2048), dim3(256), 0, stream,
                       att, psum);
}